// Round 2
// baseline (161.346 us; speedup 1.0000x reference)
//
#include <hip/hip_runtime.h>

// Problem constants (B=4, S=2048, D=1024, O=1024, C=8)
#define TOK   8192
#define DIM   1024
#define OUTD  1024
#define NCAT  8
#define BM    128
#define BN    128
#define BK    32
#define MAX_MT 71                 // sum ceil(n_c/128) <= 8192/128 + 7 = 71
#define MPMAX (MAX_MT * BM)       // 9088 padded rows

typedef __attribute__((ext_vector_type(8))) __bf16 bf16x8;
typedef __attribute__((ext_vector_type(4))) float  f32x4;

__device__ __forceinline__ unsigned short f2bf(float f) {
  unsigned u = __float_as_uint(f);
  u += 0x7fffu + ((u >> 16) & 1u);      // RNE, fine for non-NaN inputs
  return (unsigned short)(u >> 16);
}

// ---------------- K1: bucket tokens by category (ballot-based, no atomics) --
__global__ __launch_bounds__(1024) void k_build(const int* __restrict__ cid,
    int* __restrict__ row_token, int* __restrict__ tile_c, int* __restrict__ tile_m) {
  __shared__ int wcnt[16][NCAT];    // per-wave per-cat counts
  __shared__ int wbase[16][NCAT];   // per-wave offset within cat
  __shared__ int gbase[NCAT];       // padded global base per cat
  int tid = threadIdx.x, lane = tid & 63, wave = tid >> 6;
  int base = wave * 512;

  // phase 1: per-wave counts via ballot
  int cs[8];
  #pragma unroll
  for (int it = 0; it < 8; ++it) cs[it] = cid[base + it * 64 + lane];
  int cnt_loc[NCAT];
  #pragma unroll
  for (int c = 0; c < NCAT; ++c) cnt_loc[c] = 0;
  #pragma unroll
  for (int it = 0; it < 8; ++it) {
    #pragma unroll
    for (int c = 0; c < NCAT; ++c) {
      unsigned long long m = __ballot(cs[it] == c);
      cnt_loc[c] += __popcll(m);
    }
  }
  if (lane == 0) {
    #pragma unroll
    for (int c = 0; c < NCAT; ++c) wcnt[wave][c] = cnt_loc[c];
  }
  __syncthreads();

  // phase 2: serial scan (8 cats x 16 waves) + tile table
  if (tid == 0) {
    int pr = 0, mt = 0;
    for (int c = 0; c < NCAT; ++c) {
      int tot = 0;
      for (int w = 0; w < 16; ++w) { wbase[w][c] = tot; tot += wcnt[w][c]; }
      gbase[c] = pr;
      int nt = (tot + BM - 1) / BM;
      for (int i = 0; i < nt; ++i) { tile_c[mt] = c; tile_m[mt] = pr + i * BM; ++mt; }
      pr += nt * BM;
    }
    for (; mt < MAX_MT; ++mt) { tile_c[mt] = -1; tile_m[mt] = 0; }
  }
  __syncthreads();
  for (int r = tid; r < MPMAX; r += 1024) row_token[r] = -1;
  __syncthreads();

  // phase 3: deterministic scatter via prefix-popcount
  int run[NCAT];
  #pragma unroll
  for (int c = 0; c < NCAT; ++c) run[c] = gbase[c] + wbase[wave][c];
  unsigned long long lt = (lane == 63) ? ~0ull >> 1 : ((1ull << lane) - 1);
  #pragma unroll
  for (int it = 0; it < 8; ++it) {
    int t = base + it * 64 + lane;
    int c = cs[it];
    int pos = 0;
    #pragma unroll
    for (int cat = 0; cat < NCAT; ++cat) {
      unsigned long long m = __ballot(cs[it] == cat);
      if (cat == c) pos = run[cat] + __popcll(m & lt);
      run[cat] += __popcll(m);
    }
    row_token[pos] = t;
  }
}

// ---------------- K2: fused {weight transpose+convert} + {x gather+convert} --
// blocks [0, 2048): wt[c][o][d] bf16 from w[c][d][o] fp32, 64x64 tiles
// blocks [2048, 2048+4544): xg[r][d] bf16 gathered via row_token
__global__ __launch_bounds__(256) void k_convert(const float* __restrict__ w,
    const float* __restrict__ x, const int* __restrict__ row_token,
    unsigned short* __restrict__ wt, unsigned short* __restrict__ xg) {
  int tid = threadIdx.x;
  if (blockIdx.x < 2048) {
    int b = blockIdx.x;
    int ot = b & 15, dt = (b >> 4) & 15, c = b >> 8;
    __shared__ unsigned short t[64][72];              // +8: rows stay 16B-aligned
    int i  = tid >> 2;        // 0..63
    int jg = tid & 3;         // 0..3 (16 floats each)
    const float* src = w + ((size_t)c << 20) + (size_t)(dt * 64 + i) * 1024 + ot * 64 + jg * 16;
    #pragma unroll
    for (int q = 0; q < 4; ++q) {
      float4 v = *(const float4*)(src + q * 4);
      t[jg * 16 + q * 4 + 0][i] = f2bf(v.x);
      t[jg * 16 + q * 4 + 1][i] = f2bf(v.y);
      t[jg * 16 + q * 4 + 2][i] = f2bf(v.z);
      t[jg * 16 + q * 4 + 3][i] = f2bf(v.w);
    }
    __syncthreads();
    unsigned short* dst = wt + ((size_t)c << 20) + (size_t)(ot * 64 + i) * 1024 + dt * 64 + jg * 16;
    uint4 a = *(const uint4*)&t[i][jg * 16];
    uint4 bq = *(const uint4*)&t[i][jg * 16 + 8];
    *(uint4*)dst = a;
    *(uint4*)(dst + 8) = bq;
  } else {
    int idx = (blockIdx.x - 2048) * 256 + tid;        // one thread per 8 elements
    int r  = idx >> 7;
    int e0 = (idx & 127) << 3;
    if (r >= MPMAX) return;
    int tok = row_token[r];
    union { unsigned short u[8]; uint4 v; } o;
    if (tok >= 0) {
      const float4* s = (const float4*)(x + (size_t)tok * DIM + e0);
      float4 a = s[0], b = s[1];
      o.u[0] = f2bf(a.x); o.u[1] = f2bf(a.y); o.u[2] = f2bf(a.z); o.u[3] = f2bf(a.w);
      o.u[4] = f2bf(b.x); o.u[5] = f2bf(b.y); o.u[6] = f2bf(b.z); o.u[7] = f2bf(b.w);
    } else {
      o.v = make_uint4(0u, 0u, 0u, 0u);
    }
    *(uint4*)(xg + (size_t)r * DIM + e0) = o.v;
  }
}

// ---------------- K3: grouped GEMM, 2-phase double-buffered 128x128x32 ------
__global__ __launch_bounds__(256) void k_gemm(const unsigned short* __restrict__ xg,
    const unsigned short* __restrict__ wt, const float* __restrict__ bias,
    const int* __restrict__ row_token, const int* __restrict__ tile_c,
    const int* __restrict__ tile_m, float* __restrict__ out) {
  int mt = blockIdx.y;
  int c = tile_c[mt];
  if (c < 0) return;
  int m0 = tile_m[mt];
  int n0 = blockIdx.x * BN;

  __shared__ unsigned short As[2][BM][BK];
  __shared__ unsigned short Bs[2][BM][BK];

  int tid  = threadIdx.x;
  int lane = tid & 63;
  int wave = tid >> 6;
  int wr = wave >> 1, wc = wave & 1;    // 2x2 waves, 64x64 each

  f32x4 acc[4][4];
  #pragma unroll
  for (int m = 0; m < 4; ++m)
    #pragma unroll
    for (int n = 0; n < 4; ++n) acc[m][n] = (f32x4){0.f, 0.f, 0.f, 0.f};

  const unsigned short* Ag = xg + (size_t)m0 * DIM;
  const unsigned short* Bg = wt + ((size_t)c << 20) + (size_t)n0 * DIM;
  int srow = tid >> 2;            // 0..63
  int scol = (tid & 3) << 3;      // 0,8,16,24

  auto STAGE = [&](int buf, int kt) {
    __builtin_amdgcn_global_load_lds(
      (const __attribute__((address_space(1))) unsigned int*)(Ag + (size_t)srow * DIM + kt + scol),
      (__attribute__((address_space(3))) unsigned int*)(&As[buf][srow][scol]), 16, 0, 0);
    __builtin_amdgcn_global_load_lds(
      (const __attribute__((address_space(1))) unsigned int*)(Ag + (size_t)(srow + 64) * DIM + kt + scol),
      (__attribute__((address_space(3))) unsigned int*)(&As[buf][srow + 64][scol]), 16, 0, 0);
    __builtin_amdgcn_global_load_lds(
      (const __attribute__((address_space(1))) unsigned int*)(Bg + (size_t)srow * DIM + kt + scol),
      (__attribute__((address_space(3))) unsigned int*)(&Bs[buf][srow][scol]), 16, 0, 0);
    __builtin_amdgcn_global_load_lds(
      (const __attribute__((address_space(1))) unsigned int*)(Bg + (size_t)(srow + 64) * DIM + kt + scol),
      (__attribute__((address_space(3))) unsigned int*)(&Bs[buf][srow + 64][scol]), 16, 0, 0);
  };

  // prologue: stage tile 0, drain, barrier
  STAGE(0, 0);
  __syncthreads();

  int cur = 0;
  for (int kt = 0; kt < DIM - BK; kt += BK) {
    STAGE(cur ^ 1, kt + BK);      // issue next tile's loads BEFORE compute
    bf16x8 a[4], b[4];
    #pragma unroll
    for (int m = 0; m < 4; ++m)
      a[m] = *(const bf16x8*)&As[cur][wr * 64 + m * 16 + (lane & 15)][(lane >> 4) * 8];
    #pragma unroll
    for (int n = 0; n < 4; ++n)
      b[n] = *(const bf16x8*)&Bs[cur][wc * 64 + n * 16 + (lane & 15)][(lane >> 4) * 8];
    #pragma unroll
    for (int m = 0; m < 4; ++m)
      #pragma unroll
      for (int n = 0; n < 4; ++n)
        acc[m][n] = __builtin_amdgcn_mfma_f32_16x16x32_bf16(a[m], b[n], acc[m][n], 0, 0, 0);
    __syncthreads();              // drains vmcnt (next tile landed) + lgkm
    cur ^= 1;
  }
  // epilogue K-step: compute last tile (no prefetch)
  {
    bf16x8 a[4], b[4];
    #pragma unroll
    for (int m = 0; m < 4; ++m)
      a[m] = *(const bf16x8*)&As[cur][wr * 64 + m * 16 + (lane & 15)][(lane >> 4) * 8];
    #pragma unroll
    for (int n = 0; n < 4; ++n)
      b[n] = *(const bf16x8*)&Bs[cur][wc * 64 + n * 16 + (lane & 15)][(lane >> 4) * 8];
    #pragma unroll
    for (int m = 0; m < 4; ++m)
      #pragma unroll
      for (int n = 0; n < 4; ++n)
        acc[m][n] = __builtin_amdgcn_mfma_f32_16x16x32_bf16(a[m], b[n], acc[m][n], 0, 0, 0);
  }

  int col = lane & 15;
  int rq  = (lane >> 4) << 2;
  float bv[4];
  #pragma unroll
  for (int n = 0; n < 4; ++n) bv[n] = bias[c * OUTD + n0 + wc * 64 + n * 16 + col];
  #pragma unroll
  for (int m = 0; m < 4; ++m) {
    #pragma unroll
    for (int r = 0; r < 4; ++r) {
      int prow = m0 + wr * 64 + m * 16 + rq + r;
      int tok = row_token[prow];
      if (tok < 0) continue;
      float* orow = out + (size_t)tok * OUTD + n0 + wc * 64 + col;
      #pragma unroll
      for (int n = 0; n < 4; ++n) orow[n * 16] = acc[m][n][r] + bv[n];
    }
  }
}

// ---------------- launcher -------------------------------------------------
extern "C" void kernel_launch(void* const* d_in, const int* in_sizes, int n_in,
                              void* d_out, int out_size, void* d_ws, size_t ws_size,
                              hipStream_t stream) {
  const float* x    = (const float*)d_in[0];
  const int*   cid  = (const int*)d_in[1];
  const float* w    = (const float*)d_in[2];
  const float* bias = (const float*)d_in[3];
  float* out = (float*)d_out;

  // workspace carve (~35.5 MB total)
  char* ws = (char*)d_ws;
  constexpr size_t XG_BYTES = (size_t)MPMAX * DIM * 2;          // 18,612,224
  constexpr size_t WT_BYTES = (size_t)NCAT * DIM * OUTD * 2;    // 16,777,216
  constexpr size_t RT_BYTES = (size_t)MPMAX * 4;                // 36,352
  unsigned short* xg  = (unsigned short*)ws;
  unsigned short* wtb = (unsigned short*)(ws + XG_BYTES);
  int* row_token = (int*)(ws + XG_BYTES + WT_BYTES);
  int* tile_c    = (int*)(ws + XG_BYTES + WT_BYTES + RT_BYTES);
  int* tile_m    = tile_c + MAX_MT;

  k_build<<<1, 1024, 0, stream>>>(cid, row_token, tile_c, tile_m);
  // 2048 weight-transpose blocks + 4544 x-gather blocks in one dispatch
  k_convert<<<2048 + (MPMAX * (DIM / 8) + 255) / 256, 256, 0, stream>>>(w, x, row_token, wtb, xg);
  k_gemm<<<dim3(OUTD / BN, MAX_MT), 256, 0, stream>>>(xg, wtb, bias, row_token, tile_c, tile_m, out);
}

// Round 4
// 151.027 us; speedup vs baseline: 1.0683x; 1.0683x over previous
//
#include <hip/hip_runtime.h>

// Problem constants (B=4, S=2048, D=1024, O=1024, C=8)
#define TOK   8192
#define DIM   1024
#define OUTD  1024
#define NCAT  8
#define BM    128
#define BN    128
#define BK    32
#define NKT   (DIM / BK)          // 32 K-tiles
#define MAX_MT 71                 // sum ceil(n_c/128) <= 8192/128 + 7 = 71
#define MPMAX (MAX_MT * BM)       // 9088 padded rows

typedef __attribute__((ext_vector_type(8))) __bf16 bf16x8;
typedef __attribute__((ext_vector_type(4))) float  f32x4;

__device__ __forceinline__ unsigned short f2bf(float f) {
  unsigned u = __float_as_uint(f);
  u += 0x7fffu + ((u >> 16) & 1u);      // RNE, fine for non-NaN inputs
  return (unsigned short)(u >> 16);
}

// ---------------- K1: bucket tokens by category (ballot-based, no atomics) --
__global__ __launch_bounds__(1024) void k_build(const int* __restrict__ cid,
    int* __restrict__ row_token, int* __restrict__ tile_c, int* __restrict__ tile_m) {
  __shared__ int wcnt[16][NCAT];    // per-wave per-cat counts
  __shared__ int wbase[16][NCAT];   // per-wave offset within cat
  __shared__ int gbase[NCAT];       // padded global base per cat
  int tid = threadIdx.x, lane = tid & 63, wave = tid >> 6;
  int base = wave * 512;

  int cs[8];
  #pragma unroll
  for (int it = 0; it < 8; ++it) cs[it] = cid[base + it * 64 + lane];
  int cnt_loc[NCAT];
  #pragma unroll
  for (int c = 0; c < NCAT; ++c) cnt_loc[c] = 0;
  #pragma unroll
  for (int it = 0; it < 8; ++it) {
    #pragma unroll
    for (int c = 0; c < NCAT; ++c) {
      unsigned long long m = __ballot(cs[it] == c);
      cnt_loc[c] += __popcll(m);
    }
  }
  if (lane == 0) {
    #pragma unroll
    for (int c = 0; c < NCAT; ++c) wcnt[wave][c] = cnt_loc[c];
  }
  __syncthreads();

  if (tid == 0) {
    int pr = 0, mt = 0;
    for (int c = 0; c < NCAT; ++c) {
      int tot = 0;
      for (int w = 0; w < 16; ++w) { wbase[w][c] = tot; tot += wcnt[w][c]; }
      gbase[c] = pr;
      int nt = (tot + BM - 1) / BM;
      for (int i = 0; i < nt; ++i) { tile_c[mt] = c; tile_m[mt] = pr + i * BM; ++mt; }
      pr += nt * BM;
    }
    for (; mt < MAX_MT; ++mt) { tile_c[mt] = -1; tile_m[mt] = 0; }
  }
  __syncthreads();
  for (int r = tid; r < MPMAX; r += 1024) row_token[r] = -1;
  __syncthreads();

  int run[NCAT];
  #pragma unroll
  for (int c = 0; c < NCAT; ++c) run[c] = gbase[c] + wbase[wave][c];
  unsigned long long lt = (lane == 63) ? ~0ull >> 1 : ((1ull << lane) - 1);
  #pragma unroll
  for (int it = 0; it < 8; ++it) {
    int t = base + it * 64 + lane;
    int c = cs[it];
    int pos = 0;
    #pragma unroll
    for (int cat = 0; cat < NCAT; ++cat) {
      unsigned long long m = __ballot(cs[it] == cat);
      if (cat == c) pos = run[cat] + __popcll(m & lt);
      run[cat] += __popcll(m);
    }
    row_token[pos] = t;
  }
}

// ---------------- K2: fused {weight transpose+convert} + {x gather+convert} --
__global__ __launch_bounds__(256) void k_convert(const float* __restrict__ w,
    const float* __restrict__ x, const int* __restrict__ row_token,
    unsigned short* __restrict__ wt, unsigned short* __restrict__ xg) {
  int tid = threadIdx.x;
  if (blockIdx.x < 2048) {
    int b = blockIdx.x;
    int ot = b & 15, dt = (b >> 4) & 15, c = b >> 8;
    __shared__ unsigned short t[64][72];              // +8: rows stay 16B-aligned
    int i  = tid >> 2;
    int jg = tid & 3;
    const float* src = w + ((size_t)c << 20) + (size_t)(dt * 64 + i) * 1024 + ot * 64 + jg * 16;
    #pragma unroll
    for (int q = 0; q < 4; ++q) {
      float4 v = *(const float4*)(src + q * 4);
      t[jg * 16 + q * 4 + 0][i] = f2bf(v.x);
      t[jg * 16 + q * 4 + 1][i] = f2bf(v.y);
      t[jg * 16 + q * 4 + 2][i] = f2bf(v.z);
      t[jg * 16 + q * 4 + 3][i] = f2bf(v.w);
    }
    __syncthreads();
    unsigned short* dst = wt + ((size_t)c << 20) + (size_t)(ot * 64 + i) * 1024 + dt * 64 + jg * 16;
    uint4 a = *(const uint4*)&t[i][jg * 16];
    uint4 bq = *(const uint4*)&t[i][jg * 16 + 8];
    *(uint4*)dst = a;
    *(uint4*)(dst + 8) = bq;
  } else {
    int idx = (blockIdx.x - 2048) * 256 + tid;
    int r  = idx >> 7;
    int e0 = (idx & 127) << 3;
    if (r >= MPMAX) return;
    int tok = row_token[r];
    union { unsigned short u[8]; uint4 v; } o;
    if (tok >= 0) {
      const float4* s = (const float4*)(x + (size_t)tok * DIM + e0);
      float4 a = s[0], b = s[1];
      o.u[0] = f2bf(a.x); o.u[1] = f2bf(a.y); o.u[2] = f2bf(a.z); o.u[3] = f2bf(a.w);
      o.u[4] = f2bf(b.x); o.u[5] = f2bf(b.y); o.u[6] = f2bf(b.z); o.u[7] = f2bf(b.w);
    } else {
      o.v = make_uint4(0u, 0u, 0u, 0u);
    }
    *(uint4*)(xg + (size_t)r * DIM + e0) = o.v;
  }
}

// ---------------- K3: grouped GEMM, 3-deep counted-vmcnt pipeline -----------
// Tile 128x128xBK32, 4 waves (2x2), XOR-swizzled LDS, XCD-chunked block map.
__global__ __launch_bounds__(256) void k_gemm(const unsigned short* __restrict__ xg,
    const unsigned short* __restrict__ wt, const float* __restrict__ bias,
    const int* __restrict__ row_token, const int* __restrict__ tile_c,
    const int* __restrict__ tile_m, float* __restrict__ out) {
  // bijective XCD-chunked remap: grid = 568 = 8 XCDs * 71; m-major chunks so
  // each XCD owns ~9 consecutive m-tiles (A-panel + W_c stay L2-resident).
  int wg  = blockIdx.x;
  int lin = (wg & 7) * MAX_MT + (wg >> 3);   // chunk per XCD
  int mt  = lin >> 3;
  int nt  = lin & 7;
  int c = tile_c[mt];
  if (c < 0) return;
  int m0 = tile_m[mt];
  int n0 = nt * BN;

  __shared__ unsigned short As[3][BM][BK];
  __shared__ unsigned short Bs[3][BM][BK];

  int tid  = threadIdx.x;
  int lane = tid & 63;
  int wr = (tid >> 6) >> 1, wc = (tid >> 6) & 1;   // 2x2 waves, 64x64 each

  f32x4 acc[4][4];
  #pragma unroll
  for (int m = 0; m < 4; ++m)
    #pragma unroll
    for (int n = 0; n < 4; ++n) acc[m][n] = (f32x4){0.f, 0.f, 0.f, 0.f};

  const unsigned short* Ag = xg + (size_t)m0 * DIM;
  const unsigned short* Bg = wt + ((size_t)c << 20) + (size_t)n0 * DIM;

  // staging: thread tid -> LDS linear slot (row=tid>>2, col16B=tid&3); global
  // source column is XOR-swizzled so that LDS slot s at row r holds logical
  // col-group s ^ ((r>>1)&3).  (row+64 has same ((row>>1)&3) since 32%4==0.)
  int srow = tid >> 2;
  int sdst = (tid & 3) << 3;                           // LDS col, elements
  int gsrc = (((tid & 3) ^ ((tid >> 3) & 3)) << 3);    // swizzled global col

  auto STAGE = [&](int b, int kt) {
    __builtin_amdgcn_global_load_lds(
      (const __attribute__((address_space(1))) unsigned int*)(Ag + (size_t)srow * DIM + kt + gsrc),
      (__attribute__((address_space(3))) unsigned int*)(&As[b][srow][sdst]), 16, 0, 0);
    __builtin_amdgcn_global_load_lds(
      (const __attribute__((address_space(1))) unsigned int*)(Ag + (size_t)(srow + 64) * DIM + kt + gsrc),
      (__attribute__((address_space(3))) unsigned int*)(&As[b][srow + 64][sdst]), 16, 0, 0);
    __builtin_amdgcn_global_load_lds(
      (const __attribute__((address_space(1))) unsigned int*)(Bg + (size_t)srow * DIM + kt + gsrc),
      (__attribute__((address_space(3))) unsigned int*)(&Bs[b][srow][sdst]), 16, 0, 0);
    __builtin_amdgcn_global_load_lds(
      (const __attribute__((address_space(1))) unsigned int*)(Bg + (size_t)(srow + 64) * DIM + kt + gsrc),
      (__attribute__((address_space(3))) unsigned int*)(&Bs[b][srow + 64][sdst]), 16, 0, 0);
  };

  // per-lane swizzled read column: slot = g ^ ((row>>1)&3); for row =
  // base16 + (lane&15) this is g ^ (((lane&15)>>1)&3) — constant per lane.
  int rcol = (((lane >> 4) ^ ((lane & 15) >> 1 & 3)) << 3);
  int arow = wr * 64 + (lane & 15);
  int brow = wc * 64 + (lane & 15);

  // prologue: 3 tiles in flight (12 loads/thread), no drain
  STAGE(0, 0); STAGE(1, BK); STAGE(2, 2 * BK);

  int b = 0;
  for (int t = 0; t < NKT; ++t) {
    // wait for tile t only: (in-flight-1)*4 loads may remain outstanding
    if (t < NKT - 2)       asm volatile("s_waitcnt vmcnt(8)" ::: "memory");
    else if (t == NKT - 2) asm volatile("s_waitcnt vmcnt(4)" ::: "memory");
    else                   asm volatile("s_waitcnt vmcnt(0)" ::: "memory");
    __builtin_amdgcn_s_barrier();          // tile t resident for all waves

    bf16x8 af[4], bf[4];
    #pragma unroll
    for (int m = 0; m < 4; ++m)
      af[m] = *(const bf16x8*)&As[b][arow + m * 16][rcol];
    #pragma unroll
    for (int n = 0; n < 4; ++n)
      bf[n] = *(const bf16x8*)&Bs[b][brow + n * 16][rcol];
    #pragma unroll
    for (int m = 0; m < 4; ++m)
      #pragma unroll
      for (int n = 0; n < 4; ++n)
        acc[m][n] = __builtin_amdgcn_mfma_f32_16x16x32_bf16(af[m], bf[n], acc[m][n], 0, 0, 0);

    __builtin_amdgcn_s_barrier();          // all waves done reading buf b
    if (t < NKT - 3) STAGE(b, (t + 3) * BK);
    b = (b == 2) ? 0 : b + 1;
  }

  int col = lane & 15;
  int rq  = (lane >> 4) << 2;
  float bv[4];
  #pragma unroll
  for (int n = 0; n < 4; ++n) bv[n] = bias[c * OUTD + n0 + wc * 64 + n * 16 + col];
  #pragma unroll
  for (int m = 0; m < 4; ++m) {
    #pragma unroll
    for (int r = 0; r < 4; ++r) {
      int prow = m0 + wr * 64 + m * 16 + rq + r;
      int tok = row_token[prow];
      if (tok < 0) continue;
      float* orow = out + (size_t)tok * OUTD + n0 + wc * 64 + col;
      #pragma unroll
      for (int n = 0; n < 4; ++n) orow[n * 16] = acc[m][n][r] + bv[n];
    }
  }
}

// ---------------- launcher -------------------------------------------------
extern "C" void kernel_launch(void* const* d_in, const int* in_sizes, int n_in,
                              void* d_out, int out_size, void* d_ws, size_t ws_size,
                              hipStream_t stream) {
  const float* x    = (const float*)d_in[0];
  const int*   cid  = (const int*)d_in[1];
  const float* w    = (const float*)d_in[2];
  const float* bias = (const float*)d_in[3];
  float* out = (float*)d_out;

  char* ws = (char*)d_ws;
  constexpr size_t XG_BYTES = (size_t)MPMAX * DIM * 2;          // 18,612,224
  constexpr size_t WT_BYTES = (size_t)NCAT * DIM * OUTD * 2;    // 16,777,216
  constexpr size_t RT_BYTES = (size_t)MPMAX * 4;                // 36,352
  unsigned short* xg  = (unsigned short*)ws;
  unsigned short* wtb = (unsigned short*)(ws + XG_BYTES);
  int* row_token = (int*)(ws + XG_BYTES + WT_BYTES);
  int* tile_c    = (int*)(ws + XG_BYTES + WT_BYTES + RT_BYTES);
  int* tile_m    = tile_c + MAX_MT;

  k_build<<<1, 1024, 0, stream>>>(cid, row_token, tile_c, tile_m);
  k_convert<<<2048 + (MPMAX * (DIM / 8) + 255) / 256, 256, 0, stream>>>(w, x, row_token, wtb, xg);
  k_gemm<<<8 * MAX_MT, 256, 0, stream>>>(xg, wtb, bias, row_token, tile_c, tile_m, out);
}